// Round 1
// baseline (478.962 us; speedup 1.0000x reference)
//
#include <hip/hip_runtime.h>
#include <hip/hip_bf16.h>
#include <stdint.h>

// Problem constants (B,C,H,W = 32,256,64,64; E=4, O=256, K=3)
#define NB 32
#define NC 256
#define NH 64
#define NW 64
#define NE 4
#define NO 256

typedef __bf16 bf16x8 __attribute__((ext_vector_type(8)));
typedef float  f32x4  __attribute__((ext_vector_type(4)));

__device__ __forceinline__ unsigned short f2bf(float f) {
  union { float f; uint32_t u; } v; v.f = f;
  uint32_t u = v.u;
  uint32_t r = (u + 0x7FFFu + ((u >> 16) & 1u)) >> 16;  // RNE
  return (unsigned short)r;
}

// ---------------- Kernel 1: global average pool  pooled[b*C+c] ----------------
__global__ __launch_bounds__(256) void pool_k(const float* __restrict__ x,
                                              float* __restrict__ pooled) {
  const int bc  = blockIdx.x;                // b*NC + c
  const int tid = threadIdx.x;
  const float4* base = (const float4*)(x + (size_t)bc * (NH * NW));
  float s = 0.f;
#pragma unroll
  for (int i = 0; i < 4; ++i) {
    float4 v = base[tid + 256 * i];
    s += v.x + v.y + v.z + v.w;
  }
#pragma unroll
  for (int off = 32; off > 0; off >>= 1) s += __shfl_down(s, off, 64);
  __shared__ float ws[4];
  if ((tid & 63) == 0) ws[tid >> 6] = s;
  __syncthreads();
  if (tid == 0) pooled[bc] = (ws[0] + ws[1] + ws[2] + ws[3]) * (1.f / (NH * NW));
}

// ---------------- Kernel 2: router logits + softmax -> attn[b*E+e] ----------------
__global__ __launch_bounds__(64) void router_k(const float* __restrict__ pooled,
                                               const float* __restrict__ rw,
                                               const float* __restrict__ rb,
                                               float* __restrict__ attn) {
  const int b = blockIdx.x, t = threadIdx.x;
  float p0 = 0.f, p1 = 0.f, p2 = 0.f, p3 = 0.f;
  for (int c = t; c < NC; c += 64) {
    float pv = pooled[b * NC + c];
    p0 += pv * rw[0 * NC + c];
    p1 += pv * rw[1 * NC + c];
    p2 += pv * rw[2 * NC + c];
    p3 += pv * rw[3 * NC + c];
  }
#pragma unroll
  for (int off = 32; off > 0; off >>= 1) {
    p0 += __shfl_down(p0, off, 64);
    p1 += __shfl_down(p1, off, 64);
    p2 += __shfl_down(p2, off, 64);
    p3 += __shfl_down(p3, off, 64);
  }
  if (t == 0) {
    float l0 = p0 + rb[0], l1 = p1 + rb[1], l2 = p2 + rb[2], l3 = p3 + rb[3];
    float m  = fmaxf(fmaxf(l0, l1), fmaxf(l2, l3));
    float e0 = expf(l0 - m), e1 = expf(l1 - m), e2 = expf(l2 - m), e3 = expf(l3 - m);
    float inv = 1.f / (e0 + e1 + e2 + e3);
    attn[b * 4 + 0] = e0 * inv;
    attn[b * 4 + 1] = e1 * inv;
    attn[b * 4 + 2] = e2 * inv;
    attn[b * 4 + 3] = e3 * inv;
  }
}

// ---------------- Kernel 3: mixed weights, bf16, conv-staging layout ----------------
// wmix elem index = ((b*9 + t)*8 + cb)*8192 + o*32 + c32   (t=kh*3+kw, c = cb*32+c32)
// 18,874,368 bf16 elements = 37.75 MB in d_ws.
__global__ __launch_bounds__(256) void wmix_k(const float* __restrict__ ew,
                                              const float* __restrict__ attn,
                                              unsigned short* __restrict__ wmix) {
  const int i   = blockIdx.x * 256 + threadIdx.x;   // exact grid
  const int c32 = i & 31;
  const int o   = (i >> 5) & 255;
  const int cb  = (i >> 13) & 7;
  const int rest = i >> 16;                         // b*9 + t
  const int t = rest % 9;
  const int b = rest / 9;
  const int c = cb * 32 + c32;
  const float a0 = attn[b * 4 + 0], a1 = attn[b * 4 + 1];
  const float a2 = attn[b * 4 + 2], a3 = attn[b * 4 + 3];
  const size_t estride = (size_t)NO * NC * 9;       // per-expert stride
  const size_t wi = ((size_t)o * NC + c) * 9 + t;
  float s = a0 * ew[wi] + a1 * ew[wi + estride] + a2 * ew[wi + 2 * estride] +
            a3 * ew[wi + 3 * estride];
  wmix[i] = f2bf(s);
}

// ---------------- Kernel 4: implicit-GEMM conv with per-sample weights ----------------
// Block: 128 O x 128 pixels (2 image rows). 4 waves, each 64x64 (4x4 mfma frags).
// K-loop: 8 c-chunks (32 ch) x 9 taps, BK=32 per MFMA.
__global__ __launch_bounds__(256) void conv_k(const float* __restrict__ x,
                                              const unsigned short* __restrict__ wmix,
                                              float* __restrict__ y) {
  const int ptile = blockIdx.x;          // 0..31 -> rows h0, h0+1
  const int ob    = blockIdx.y * 128;    // 0 or 128
  const int b     = blockIdx.z;
  const int tid   = threadIdx.x;
  const int lane  = tid & 63;
  const int wid   = tid >> 6;
  const int wm    = (wid >> 1) * 64;     // wave's o-half within tile
  const int wrow  = wid & 1;             // wave's pixel row within tile
  const int h0    = ptile * 2;

  const int lm = lane & 15;
  const int lq = lane >> 4;
  const int g8 = lq * 8;

  __shared__ unsigned short xlds[4 * 66 * 32];   // [row][col][c32], 16896 B
  __shared__ unsigned short wlds[2][128 * 32];   // double-buffered W tap tile, 2x8192 B

  f32x4 acc[4][4];
#pragma unroll
  for (int i = 0; i < 4; ++i)
#pragma unroll
    for (int j = 0; j < 4; ++j) acc[i][j] = {0.f, 0.f, 0.f, 0.f};

  // X staging thread mapping: tid = sr*64 + scg*16 + scp
  const int sr  = tid >> 6;          // halo row 0..3 (global h0-1+sr)
  const int scp = tid & 15;          // channel pair -> c = 2*scp, 2*scp+1
  const int scg = (tid >> 4) & 3;    // column group: cols scg, scg+4, ...
  const int gh  = h0 - 1 + sr;
  const bool hok = (gh >= 0) && (gh < NH);

  for (int cb = 0; cb < 8; ++cb) {
    // ---- stage X halo tile (32 channels) -> LDS bf16, zero-padded borders
    {
      const float* xr0 =
          x + (((size_t)(b * NC + cb * 32 + 2 * scp) * NH + (hok ? gh : 0)) * NW);
      const float* xr1 = xr0 + (size_t)NH * NW;  // next channel
      for (int k = 0; k < 17; ++k) {
        int col = scg + 4 * k;
        if (col < 66) {
          int w   = col - 1;
          bool ok = hok && (w >= 0) && (w < NW);
          float f0 = ok ? xr0[w] : 0.f;
          float f1 = ok ? xr1[w] : 0.f;
          uint32_t pk = (uint32_t)f2bf(f0) | ((uint32_t)f2bf(f1) << 16);
          *(uint32_t*)&xlds[(sr * 66 + col) * 32 + 2 * scp] = pk;
        }
      }
    }

    // ---- W tap staging via global_load_lds (width 16), linear LDS dest
    const size_t wchunk = (size_t)(b * 9) * 65536 + (size_t)cb * 8192 + (size_t)ob * 32;
    auto stageW = [&](int t, int buf) {
      const unsigned short* src = wmix + wchunk + (size_t)t * 65536 + tid * 8;
      char* dst = (char*)&wlds[buf][0] + (tid >> 6) * 1024;
      __builtin_amdgcn_global_load_lds((const __attribute__((address_space(1))) void*)src,
                                       (__attribute__((address_space(3))) void*)dst,
                                       16, 0, 0);
      __builtin_amdgcn_global_load_lds(
          (const __attribute__((address_space(1))) void*)(src + 2048),
          (__attribute__((address_space(3))) void*)(dst + 4096), 16, 0, 0);
    };
    stageW(0, 0);
    __syncthreads();  // X writes + W tap-0 visible

#pragma unroll
    for (int t = 0; t < 9; ++t) {
      if (t < 8) stageW(t + 1, (t + 1) & 1);
      const int kh = t / 3, kw = t % 3;
      const unsigned short* wb = &wlds[t & 1][0];
      bf16x8 af[4], bfr[4];
#pragma unroll
      for (int mf = 0; mf < 4; ++mf)
        af[mf] = *(const bf16x8*)&wb[(wm + mf * 16 + lm) * 32 + g8];
#pragma unroll
      for (int nf = 0; nf < 4; ++nf)
        bfr[nf] = *(const bf16x8*)&xlds[((wrow + kh) * 66 + (nf * 16 + lm + kw)) * 32 + g8];
#pragma unroll
      for (int mf = 0; mf < 4; ++mf)
#pragma unroll
        for (int nf = 0; nf < 4; ++nf)
          acc[mf][nf] =
              __builtin_amdgcn_mfma_f32_16x16x32_bf16(af[mf], bfr[nf], acc[mf][nf], 0, 0, 0);
      __syncthreads();  // drains next-tap gload_lds; protects buffer swap + xlds restage
    }
  }

  // ---- epilogue: D row = o (4*lq+i within frag), col = pixel
  const int h = h0 + wrow;
#pragma unroll
  for (int mf = 0; mf < 4; ++mf) {
#pragma unroll
    for (int nf = 0; nf < 4; ++nf) {
      f32x4 v = acc[mf][nf];
      int wcol = nf * 16 + lm;
#pragma unroll
      for (int i = 0; i < 4; ++i) {
        int o = ob + wm + mf * 16 + lq * 4 + i;
        y[(((size_t)b * NO + o) * NH + h) * NW + wcol] = v[i];
      }
    }
  }
}

extern "C" void kernel_launch(void* const* d_in, const int* in_sizes, int n_in,
                              void* d_out, int out_size, void* d_ws, size_t ws_size,
                              hipStream_t stream) {
  const float* x  = (const float*)d_in[0];   // [32,256,64,64]
  const float* rw = (const float*)d_in[1];   // [4,256,1,1]
  const float* rb = (const float*)d_in[2];   // [4]
  const float* ew = (const float*)d_in[3];   // [4,256,256,3,3]
  float* yout = (float*)d_out;               // [32,256,64,64] fp32

  // workspace layout: pooled (32KB) | attn (512B) | ... | wmix bf16 @64KB (37.75MB)
  float* pooled = (float*)d_ws;
  float* attn   = pooled + NB * NC;
  unsigned short* wmix = (unsigned short*)((char*)d_ws + 65536);

  pool_k<<<NB * NC, 256, 0, stream>>>(x, pooled);
  router_k<<<NB, 64, 0, stream>>>(pooled, rw, rb, attn);
  wmix_k<<<73728, 256, 0, stream>>>(ew, attn, wmix);      // 73728*256 = 18,874,368
  conv_k<<<dim3(32, 2, 32), 256, 0, stream>>>(x, wmix, yout);
}

// Round 2
// 241.804 us; speedup vs baseline: 1.9808x; 1.9808x over previous
//
#include <hip/hip_runtime.h>
#include <hip/hip_bf16.h>
#include <stdint.h>

// Problem constants (B,C,H,W = 32,256,64,64; E=4, O=256, K=3)
#define NB 32
#define NC 256
#define NH 64
#define NW 64
#define NE 4
#define NO 256

typedef __bf16 bf16x8 __attribute__((ext_vector_type(8)));
typedef float  f32x4  __attribute__((ext_vector_type(4)));

__device__ __forceinline__ unsigned short f2bf(float f) {
  union { float f; uint32_t u; } v; v.f = f;
  uint32_t u = v.u;
  uint32_t r = (u + 0x7FFFu + ((u >> 16) & 1u)) >> 16;  // RNE
  return (unsigned short)r;
}

// =====================================================================
// NEW PATH
// =====================================================================

// ---- Kernel A: transpose x (NCHW fp32) -> xT (NHWC bf16) + per-(b,h) rowsums
// block = (b,h); 256 threads. LDS tile [c][w] pad-66.
__global__ __launch_bounds__(256) void xt_k(const float* __restrict__ x,
                                            unsigned short* __restrict__ xT,
                                            float* __restrict__ rowsum) {
  const int bh = blockIdx.x;            // b*64 + h
  const int tid = threadIdx.x;
  const int ci = tid >> 4;              // 0..15 channel-in-pass
  const int wq = (tid & 15) * 4;        // w quad
  __shared__ unsigned short t_lds[256 * 66];

#pragma unroll 4
  for (int p = 0; p < 16; ++p) {
    const int c = p * 16 + ci;
    const float4 v = *(const float4*)&x[(((size_t)(blockIdx.x >> 6) * 256 + c) * 64 +
                                         (bh & 63)) * 64 + wq];
    uint32_t p0 = (uint32_t)f2bf(v.x) | ((uint32_t)f2bf(v.y) << 16);
    uint32_t p1 = (uint32_t)f2bf(v.z) | ((uint32_t)f2bf(v.w) << 16);
    *(uint32_t*)&t_lds[c * 66 + wq]     = p0;
    *(uint32_t*)&t_lds[c * 66 + wq + 2] = p1;
    float s = (v.x + v.y) + (v.z + v.w);
    s += __shfl_down(s, 8, 16);
    s += __shfl_down(s, 4, 16);
    s += __shfl_down(s, 2, 16);
    s += __shfl_down(s, 1, 16);
    if ((tid & 15) == 0) rowsum[((size_t)bh << 8) + c] = s;
  }
  __syncthreads();
#pragma unroll
  for (int i = 0; i < 8; ++i) {
    const int m  = tid + (i << 8);
    const int w  = m >> 5;
    const int cg = m & 31;
    uint32_t q0 = (uint32_t)t_lds[(cg * 8 + 0) * 66 + w] |
                  ((uint32_t)t_lds[(cg * 8 + 1) * 66 + w] << 16);
    uint32_t q1 = (uint32_t)t_lds[(cg * 8 + 2) * 66 + w] |
                  ((uint32_t)t_lds[(cg * 8 + 3) * 66 + w] << 16);
    uint32_t q2 = (uint32_t)t_lds[(cg * 8 + 4) * 66 + w] |
                  ((uint32_t)t_lds[(cg * 8 + 5) * 66 + w] << 16);
    uint32_t q3 = (uint32_t)t_lds[(cg * 8 + 6) * 66 + w] |
                  ((uint32_t)t_lds[(cg * 8 + 7) * 66 + w] << 16);
    uint4 q = {q0, q1, q2, q3};
    *(uint4*)&xT[(((size_t)bh << 6) + w) * 256 + cg * 8] = q;
  }
}

// ---- Kernel B: reduce rowsums -> pooled -> logits -> softmax -> attn; zero zpage
__global__ __launch_bounds__(256) void router2_k(const float* __restrict__ rowsum,
                                                 const float* __restrict__ rw,
                                                 const float* __restrict__ rb,
                                                 float* __restrict__ attn,
                                                 uint32_t* __restrict__ zpage) {
  const int b = blockIdx.x, tid = threadIdx.x;
  if (b == 0) { uint4 z = {0, 0, 0, 0}; ((uint4*)zpage)[tid] = z; }
  float s = 0.f;
#pragma unroll 8
  for (int h = 0; h < 64; ++h) s += rowsum[((size_t)(b * 64 + h) << 8) + tid];
  __shared__ float pl[256];
  __shared__ float lg[4];
  pl[tid] = s * (1.f / 4096.f);
  __syncthreads();
  const int e = tid >> 6, ln = tid & 63;
  float d = pl[ln]       * rw[e * 256 + ln] +
            pl[ln + 64]  * rw[e * 256 + ln + 64] +
            pl[ln + 128] * rw[e * 256 + ln + 128] +
            pl[ln + 192] * rw[e * 256 + ln + 192];
#pragma unroll
  for (int off = 32; off > 0; off >>= 1) d += __shfl_down(d, off, 64);
  if (ln == 0) lg[e] = d + rb[e];
  __syncthreads();
  if (tid == 0) {
    float l0 = lg[0], l1 = lg[1], l2 = lg[2], l3 = lg[3];
    float m  = fmaxf(fmaxf(l0, l1), fmaxf(l2, l3));
    float e0 = expf(l0 - m), e1 = expf(l1 - m), e2 = expf(l2 - m), e3 = expf(l3 - m);
    float inv = 1.f / (e0 + e1 + e2 + e3);
    attn[b * 4 + 0] = e0 * inv;
    attn[b * 4 + 1] = e1 * inv;
    attn[b * 4 + 2] = e2 * inv;
    attn[b * 4 + 3] = e3 * inv;
  }
}

// ---- Kernel C: mixed weights; each thread owns one (t,cb,o,c32), loops over b
// wmix elem = b*589824 + ((t*8 + cb)*8192) + o*32 + c32
__global__ __launch_bounds__(256) void wmix_k2(const float* __restrict__ ew,
                                               const float* __restrict__ attn,
                                               unsigned short* __restrict__ wmix) {
  __shared__ float at[128];
  if (threadIdx.x < 128) at[threadIdx.x] = attn[threadIdx.x];
  __syncthreads();
  const int i   = blockIdx.x * 256 + threadIdx.x;   // 0..589823
  const int c32 = i & 31;
  const int o   = (i >> 5) & 255;
  const int cb  = (i >> 13) & 7;
  const int t   = i >> 16;                          // 0..8
  const int c   = cb * 32 + c32;
  const size_t estride = (size_t)NO * NC * 9;       // 589824
  const size_t wi = ((size_t)o * NC + c) * 9 + t;
  const float e0 = ew[wi], e1 = ew[wi + estride], e2 = ew[wi + 2 * estride],
              e3 = ew[wi + 3 * estride];
  const size_t outbase = ((size_t)t * 8 + cb) * 8192 + o * 32 + c32;
#pragma unroll 4
  for (int b = 0; b < 32; ++b) {
    float s = at[b * 4] * e0 + at[b * 4 + 1] * e1 + at[b * 4 + 2] * e2 +
              at[b * 4 + 3] * e3;
    wmix[outbase + (size_t)b * 589824] = f2bf(s);
  }
}

// ---- Kernel D: implicit-GEMM conv. W global->reg (pipelined); X gload_lds,
// double-buffered, XOR-swizzled (inverse-swizzle on source). 1 barrier / c-chunk.
__global__ __launch_bounds__(256, 3) void conv_k2(
    const unsigned short* __restrict__ xT, const unsigned short* __restrict__ wmix,
    const unsigned short* __restrict__ zpage, float* __restrict__ y) {
  // XCD-aware decode: xcd = bid&7 -> each XCD sweeps one b at a time
  const int bid   = blockIdx.x;
  const int r     = bid >> 3;
  const int ptile = r & 31;
  const int ob    = ((r >> 5) & 1) * 128;
  const int b     = (bid & 7) + ((r >> 6) << 3);
  const int tid   = threadIdx.x;
  const int lane  = tid & 63;
  const int wid   = tid >> 6;
  const int wm    = (wid >> 1) * 64;
  const int wrow  = wid & 1;
  const int h0    = ptile * 2;
  const int lm    = lane & 15;
  const int lq    = lane >> 4;

  __shared__ unsigned short xlds[2][8704];  // 17408 B per buffer (16896 used + pad)

  // --- staging precompute: 5 chunks of 1KB per wave; dest d = chunk*64+lane (16B units)
  // tile unit d -> (row = d/264, col = (d%264)>>2, slot = d&3); stored channel-group
  // g = slot ^ ((col>>1)&3)  [inverse swizzle on the SOURCE]
  const unsigned short* sptr[5];
  uint32_t cbadd[5];
#pragma unroll
  for (int i = 0; i < 5; ++i) {
    const int chunk = wid + 4 * i;
    const int d   = chunk * 64 + lane;
    const int row = d / 264;
    const int rem = d - row * 264;
    const int col = rem >> 2;
    const int s   = rem & 3;
    const int g   = s ^ ((col >> 1) & 3);
    const int gh  = h0 - 1 + row;
    const int w   = col - 1;
    const bool ok = (d < 1056) && (gh >= 0) && (gh < NH) && (w >= 0) && (w < NW);
    sptr[i]  = ok ? xT + (((size_t)((b * 64 + gh) * 64 + w)) << 8) + g * 8
                  : zpage + lane * 8;
    cbadd[i] = ok ? 32u : 0u;
  }

  auto stage = [&](int cbv, int buf) {
#pragma unroll
    for (int i = 0; i < 5; ++i) {
      if (wid + 4 * i < 17) {
        const unsigned short* src = sptr[i] + cbadd[i] * (uint32_t)cbv;
        char* dst = (char*)&xlds[buf][0] + (wid + 4 * i) * 1024;
        __builtin_amdgcn_global_load_lds(
            (const __attribute__((address_space(1))) void*)src,
            (__attribute__((address_space(3))) void*)dst, 16, 0, 0);
      }
    }
  };

  f32x4 acc[4][4];
#pragma unroll
  for (int i = 0; i < 4; ++i)
#pragma unroll
    for (int j = 0; j < 4; ++j) acc[i][j] = {0.f, 0.f, 0.f, 0.f};

  const unsigned short* wbase =
      wmix + (size_t)b * 589824 + (ob + wm + lm) * 32 + lq * 8;

#define LOADA(d0, d1, d2, d3, cbv, tv)                                        \
  {                                                                           \
    const unsigned short* wp = wbase + (size_t)((tv) * 8 + (cbv)) * 8192;     \
    d0 = *(const bf16x8*)wp;                                                  \
    d1 = *(const bf16x8*)(wp + 512);                                          \
    d2 = *(const bf16x8*)(wp + 1024);                                         \
    d3 = *(const bf16x8*)(wp + 1536);                                         \
  }

  bf16x8 a0, a1, a2, a3, n0, n1, n2, n3;
  stage(0, 0);
  LOADA(a0, a1, a2, a3, 0, 0);
  __syncthreads();  // X(0) ready

  for (int cb = 0; cb < 8; ++cb) {
    const int cur = cb & 1;
    if (cb < 7) stage(cb + 1, cur ^ 1);
    const char* xb = (const char*)&xlds[cur][0];
#pragma unroll
    for (int t = 0; t < 9; ++t) {
      const int nt  = (t == 8) ? 0 : t + 1;
      const int ncb = (t == 8) ? cb + 1 : cb;
      const int ccb = ncb < 8 ? ncb : 7;
      LOADA(n0, n1, n2, n3, ccb, nt);
      const int kh = t / 3, kw = t - kh * 3;
      const int rb66 = (wrow + kh) * 66;
      bf16x8 x0, x1, x2, x3;
      {
        const int col = lm + kw;
        x0 = *(const bf16x8*)(xb + (((rb66 + col) << 6) | ((lq ^ ((col >> 1) & 3)) << 4)));
      }
      {
        const int col = 16 + lm + kw;
        x1 = *(const bf16x8*)(xb + (((rb66 + col) << 6) | ((lq ^ ((col >> 1) & 3)) << 4)));
      }
      {
        const int col = 32 + lm + kw;
        x2 = *(const bf16x8*)(xb + (((rb66 + col) << 6) | ((lq ^ ((col >> 1) & 3)) << 4)));
      }
      {
        const int col = 48 + lm + kw;
        x3 = *(const bf16x8*)(xb + (((rb66 + col) << 6) | ((lq ^ ((col >> 1) & 3)) << 4)));
      }
      acc[0][0] = __builtin_amdgcn_mfma_f32_16x16x32_bf16(a0, x0, acc[0][0], 0, 0, 0);
      acc[0][1] = __builtin_amdgcn_mfma_f32_16x16x32_bf16(a0, x1, acc[0][1], 0, 0, 0);
      acc[0][2] = __builtin_amdgcn_mfma_f32_16x16x32_bf16(a0, x2, acc[0][2], 0, 0, 0);
      acc[0][3] = __builtin_amdgcn_mfma_f32_16x16x32_bf16(a0, x3, acc[0][3], 0, 0, 0);
      acc[1][0] = __builtin_amdgcn_mfma_f32_16x16x32_bf16(a1, x0, acc[1][0], 0, 0, 0);
      acc[1][1] = __builtin_amdgcn_mfma_f32_16x16x32_bf16(a1, x1, acc[1][1], 0, 0, 0);
      acc[1][2] = __builtin_amdgcn_mfma_f32_16x16x32_bf16(a1, x2, acc[1][2], 0, 0, 0);
      acc[1][3] = __builtin_amdgcn_mfma_f32_16x16x32_bf16(a1, x3, acc[1][3], 0, 0, 0);
      acc[2][0] = __builtin_amdgcn_mfma_f32_16x16x32_bf16(a2, x0, acc[2][0], 0, 0, 0);
      acc[2][1] = __builtin_amdgcn_mfma_f32_16x16x32_bf16(a2, x1, acc[2][1], 0, 0, 0);
      acc[2][2] = __builtin_amdgcn_mfma_f32_16x16x32_bf16(a2, x2, acc[2][2], 0, 0, 0);
      acc[2][3] = __builtin_amdgcn_mfma_f32_16x16x32_bf16(a2, x3, acc[2][3], 0, 0, 0);
      acc[3][0] = __builtin_amdgcn_mfma_f32_16x16x32_bf16(a3, x0, acc[3][0], 0, 0, 0);
      acc[3][1] = __builtin_amdgcn_mfma_f32_16x16x32_bf16(a3, x1, acc[3][1], 0, 0, 0);
      acc[3][2] = __builtin_amdgcn_mfma_f32_16x16x32_bf16(a3, x2, acc[3][2], 0, 0, 0);
      acc[3][3] = __builtin_amdgcn_mfma_f32_16x16x32_bf16(a3, x3, acc[3][3], 0, 0, 0);
      a0 = n0; a1 = n1; a2 = n2; a3 = n3;
    }
    __syncthreads();  // drains stage(cb+1); protects buffer reuse
  }

  const int h = h0 + wrow;
#pragma unroll
  for (int mf = 0; mf < 4; ++mf) {
#pragma unroll
    for (int nf = 0; nf < 4; ++nf) {
      f32x4 v = acc[mf][nf];
      const int wcol = nf * 16 + lm;
#pragma unroll
      for (int i = 0; i < 4; ++i) {
        const int o = ob + wm + mf * 16 + lq * 4 + i;
        y[(((size_t)b * NO + o) * NH + h) * NW + wcol] = v[i];
      }
    }
  }
#undef LOADA
}

// =====================================================================
// FALLBACK PATH (proven R1 kernels) — used if ws_size is too small
// =====================================================================

__global__ __launch_bounds__(256) void pool_k(const float* __restrict__ x,
                                              float* __restrict__ pooled) {
  const int bc  = blockIdx.x;
  const int tid = threadIdx.x;
  const float4* base = (const float4*)(x + (size_t)bc * (NH * NW));
  float s = 0.f;
#pragma unroll
  for (int i = 0; i < 4; ++i) {
    float4 v = base[tid + 256 * i];
    s += v.x + v.y + v.z + v.w;
  }
#pragma unroll
  for (int off = 32; off > 0; off >>= 1) s += __shfl_down(s, off, 64);
  __shared__ float ws[4];
  if ((tid & 63) == 0) ws[tid >> 6] = s;
  __syncthreads();
  if (tid == 0) pooled[bc] = (ws[0] + ws[1] + ws[2] + ws[3]) * (1.f / (NH * NW));
}

__global__ __launch_bounds__(64) void router_k(const float* __restrict__ pooled,
                                               const float* __restrict__ rw,
                                               const float* __restrict__ rb,
                                               float* __restrict__ attn) {
  const int b = blockIdx.x, t = threadIdx.x;
  float p0 = 0.f, p1 = 0.f, p2 = 0.f, p3 = 0.f;
  for (int c = t; c < NC; c += 64) {
    float pv = pooled[b * NC + c];
    p0 += pv * rw[0 * NC + c];
    p1 += pv * rw[1 * NC + c];
    p2 += pv * rw[2 * NC + c];
    p3 += pv * rw[3 * NC + c];
  }
#pragma unroll
  for (int off = 32; off > 0; off >>= 1) {
    p0 += __shfl_down(p0, off, 64);
    p1 += __shfl_down(p1, off, 64);
    p2 += __shfl_down(p2, off, 64);
    p3 += __shfl_down(p3, off, 64);
  }
  if (t == 0) {
    float l0 = p0 + rb[0], l1 = p1 + rb[1], l2 = p2 + rb[2], l3 = p3 + rb[3];
    float m  = fmaxf(fmaxf(l0, l1), fmaxf(l2, l3));
    float e0 = expf(l0 - m), e1 = expf(l1 - m), e2 = expf(l2 - m), e3 = expf(l3 - m);
    float inv = 1.f / (e0 + e1 + e2 + e3);
    attn[b * 4 + 0] = e0 * inv;
    attn[b * 4 + 1] = e1 * inv;
    attn[b * 4 + 2] = e2 * inv;
    attn[b * 4 + 3] = e3 * inv;
  }
}

__global__ __launch_bounds__(256) void conv_k(const float* __restrict__ x,
                                              const unsigned short* __restrict__ wmix,
                                              float* __restrict__ y) {
  const int ptile = blockIdx.x;
  const int ob    = blockIdx.y * 128;
  const int b     = blockIdx.z;
  const int tid   = threadIdx.x;
  const int lane  = tid & 63;
  const int wid   = tid >> 6;
  const int wm    = (wid >> 1) * 64;
  const int wrow  = wid & 1;
  const int h0    = ptile * 2;
  const int lm = lane & 15;
  const int lq = lane >> 4;
  const int g8 = lq * 8;

  __shared__ unsigned short xlds[4 * 66 * 32];
  __shared__ unsigned short wlds[2][128 * 32];

  f32x4 acc[4][4];
#pragma unroll
  for (int i = 0; i < 4; ++i)
#pragma unroll
    for (int j = 0; j < 4; ++j) acc[i][j] = {0.f, 0.f, 0.f, 0.f};

  const int sr  = tid >> 6;
  const int scp = tid & 15;
  const int scg = (tid >> 4) & 3;
  const int gh  = h0 - 1 + sr;
  const bool hok = (gh >= 0) && (gh < NH);

  for (int cb = 0; cb < 8; ++cb) {
    {
      const float* xr0 =
          x + (((size_t)(b * NC + cb * 32 + 2 * scp) * NH + (hok ? gh : 0)) * NW);
      const float* xr1 = xr0 + (size_t)NH * NW;
      for (int k = 0; k < 17; ++k) {
        int col = scg + 4 * k;
        if (col < 66) {
          int w   = col - 1;
          bool ok = hok && (w >= 0) && (w < NW);
          float f0 = ok ? xr0[w] : 0.f;
          float f1 = ok ? xr1[w] : 0.f;
          uint32_t pk = (uint32_t)f2bf(f0) | ((uint32_t)f2bf(f1) << 16);
          *(uint32_t*)&xlds[(sr * 66 + col) * 32 + 2 * scp] = pk;
        }
      }
    }
    const size_t wchunk = (size_t)(b * 9) * 65536 + (size_t)cb * 8192 + (size_t)ob * 32;
    auto stageW = [&](int t, int buf) {
      const unsigned short* src = wmix + wchunk + (size_t)t * 65536 + tid * 8;
      char* dst = (char*)&wlds[buf][0] + (tid >> 6) * 1024;
      __builtin_amdgcn_global_load_lds((const __attribute__((address_space(1))) void*)src,
                                       (__attribute__((address_space(3))) void*)dst,
                                       16, 0, 0);
      __builtin_amdgcn_global_load_lds(
          (const __attribute__((address_space(1))) void*)(src + 2048),
          (__attribute__((address_space(3))) void*)(dst + 4096), 16, 0, 0);
    };
    stageW(0, 0);
    __syncthreads();

#pragma unroll
    for (int t = 0; t < 9; ++t) {
      if (t < 8) stageW(t + 1, (t + 1) & 1);
      const int kh = t / 3, kw = t % 3;
      const unsigned short* wb = &wlds[t & 1][0];
      bf16x8 af[4], bfr[4];
#pragma unroll
      for (int mf = 0; mf < 4; ++mf)
        af[mf] = *(const bf16x8*)&wb[(wm + mf * 16 + lm) * 32 + g8];
#pragma unroll
      for (int nf = 0; nf < 4; ++nf)
        bfr[nf] = *(const bf16x8*)&xlds[((wrow + kh) * 66 + (nf * 16 + lm + kw)) * 32 + g8];
#pragma unroll
      for (int mf = 0; mf < 4; ++mf)
#pragma unroll
        for (int nf = 0; nf < 4; ++nf)
          acc[mf][nf] =
              __builtin_amdgcn_mfma_f32_16x16x32_bf16(af[mf], bfr[nf], acc[mf][nf], 0, 0, 0);
      __syncthreads();
    }
  }

  const int h = h0 + wrow;
#pragma unroll
  for (int mf = 0; mf < 4; ++mf) {
#pragma unroll
    for (int nf = 0; nf < 4; ++nf) {
      f32x4 v = acc[mf][nf];
      int wcol = nf * 16 + lm;
#pragma unroll
      for (int i = 0; i < 4; ++i) {
        int o = ob + wm + mf * 16 + lq * 4 + i;
        y[(((size_t)b * NO + o) * NH + h) * NW + wcol] = v[i];
      }
    }
  }
}

// =====================================================================

extern "C" void kernel_launch(void* const* d_in, const int* in_sizes, int n_in,
                              void* d_out, int out_size, void* d_ws, size_t ws_size,
                              hipStream_t stream) {
  const float* x  = (const float*)d_in[0];   // [32,256,64,64]
  const float* rw = (const float*)d_in[1];   // [4,256,1,1]
  const float* rb = (const float*)d_in[2];   // [4]
  const float* ew = (const float*)d_in[3];   // [4,256,256,3,3]
  float* yout = (float*)d_out;               // [32,256,64,64] fp32

  // ws layout: [0,32K) pooled | [32K,64K) attn | [64K,+37.75M) wmix |
  //            rowsum 2M | xT 67.1M | zpage 4K
  float* pooled = (float*)d_ws;
  float* attn   = (float*)((char*)d_ws + 32768);
  unsigned short* wmix = (unsigned short*)((char*)d_ws + 65536);
  const size_t OFF_ROWSUM = 65536 + 37748736;                  // 37,814,272
  const size_t OFF_XT     = OFF_ROWSUM + 2097152;              // 39,911,424
  const size_t OFF_ZERO   = OFF_XT + 67108864;                 // 107,020,288
  const size_t NEED       = OFF_ZERO + 4096;

  if (ws_size >= NEED) {
    float* rowsum = (float*)((char*)d_ws + OFF_ROWSUM);
    unsigned short* xT = (unsigned short*)((char*)d_ws + OFF_XT);
    uint32_t* zpage = (uint32_t*)((char*)d_ws + OFF_ZERO);
    xt_k<<<2048, 256, 0, stream>>>(x, xT, rowsum);
    router2_k<<<32, 256, 0, stream>>>(rowsum, rw, rb, attn, zpage);
    wmix_k2<<<2304, 256, 0, stream>>>(ew, attn, wmix);
    conv_k2<<<2048, 256, 0, stream>>>(xT, wmix, (const unsigned short*)zpage, yout);
  } else {
    pool_k<<<NB * NC, 256, 0, stream>>>(x, pooled);
    router_k<<<NB, 64, 0, stream>>>(pooled, rw, rb, attn);
    wmix_k2<<<2304, 256, 0, stream>>>(ew, attn, wmix);
    conv_k<<<dim3(32, 2, 32), 256, 0, stream>>>(x, wmix, yout);
  }
}